// Round 2
// baseline (192.536 us; speedup 1.0000x reference)
//
#include <hip/hip_runtime.h>
#include <math.h>

// SecondOrderChannelAttension on MI355X (gfx950)
// B=32, C=64, H=W=96 -> M=9216, RED=8
//
// Pipeline (3 dispatches, no atomics, no memset):
//   K1 gram_k:  per-(batch,chunk) partial Gram via bf16 MFMA 16x16x32
//               + per-chunk channel sums; direct workspace writes
//   K2 ns_k:    reduce partials, cov = Gram/M - mu mu^T, Newton-Schulz sqrt
//               (12 matmuls, bf16 MFMA in LDS, all iterates symmetric), gate MLP
//   K3 gate_mul: out = x * gate  (memory-bound elementwise)

#define BB 32
#define CC 64
#define MM 9216

typedef __attribute__((ext_vector_type(8))) short bf16x8;
typedef __attribute__((ext_vector_type(4))) float f32x4;

__device__ __forceinline__ short f2bf(float f) {
  unsigned u = __builtin_bit_cast(unsigned, f);
  return (short)(unsigned short)((u + 0x8000u) >> 16);
}
__device__ __forceinline__ float bf2f(short h) {
  unsigned u = ((unsigned)(unsigned short)h) << 16;
  return __builtin_bit_cast(float, u);
}
// truncating pack of two floats into two bf16 (1 VALU op pair, no rounding --
// bias ~0.4% max, far under the 2% output threshold)
__device__ __forceinline__ unsigned pack2(float lo, float hi) {
  unsigned ul = __builtin_bit_cast(unsigned, lo);
  unsigned uh = __builtin_bit_cast(unsigned, hi);
  return (uh & 0xffff0000u) | (ul >> 16);
}

// ---------------- K1: partial Gram + channel sums ----------------
#define NCHUNK 24
#define CHUNK_M (MM / NCHUNK)  // 384
#define WAVE_M (CHUNK_M / 4)   // 96
#define NSTEP (WAVE_M / 32)    // 3

__global__ __launch_bounds__(256, 3) void gram_k(const float* __restrict__ x,
                                                 float* __restrict__ covpart,
                                                 float* __restrict__ sumpart) {
  int b = blockIdx.x / NCHUNK;
  int chunk = blockIdx.x % NCHUNK;
  int tid = threadIdx.x;
  int w = tid >> 6, lane = tid & 63;
  int quad = lane >> 4, col = lane & 15;
  const float* xb = x + (size_t)b * CC * MM;
  int mwave = chunk * CHUNK_M + w * WAVE_M;

  f32x4 acc[4][4];
#pragma unroll
  for (int i = 0; i < 4; i++)
#pragma unroll
    for (int j = 0; j < 4; j++) acc[i][j] = (f32x4){0.f, 0.f, 0.f, 0.f};
  float csum[4] = {0.f, 0.f, 0.f, 0.f};

  const float* base[4];
#pragma unroll
  for (int rb = 0; rb < 4; rb++)
    base[rb] = xb + (size_t)(rb * 16 + col) * MM + mwave + quad * 8;

  float4 cur[4][2];
#pragma unroll
  for (int rb = 0; rb < 4; rb++) {
    cur[rb][0] = *(const float4*)(base[rb]);
    cur[rb][1] = *(const float4*)(base[rb] + 4);
  }
#pragma unroll
  for (int s = 0; s < NSTEP; s++) {
    float4 nxt[4][2];
    if (s + 1 < NSTEP) {
#pragma unroll
      for (int rb = 0; rb < 4; rb++) {
        const float* p = base[rb] + (s + 1) * 32;
        nxt[rb][0] = *(const float4*)(p);
        nxt[rb][1] = *(const float4*)(p + 4);
      }
    }
    bf16x8 frag[4];
#pragma unroll
    for (int rb = 0; rb < 4; rb++) {
      float v0 = cur[rb][0].x, v1 = cur[rb][0].y, v2 = cur[rb][0].z, v3 = cur[rb][0].w;
      float v4 = cur[rb][1].x, v5 = cur[rb][1].y, v6 = cur[rb][1].z, v7 = cur[rb][1].w;
      csum[rb] += ((v0 + v1) + (v2 + v3)) + ((v4 + v5) + (v6 + v7));
      bf16x8 f;
      unsigned* fu = (unsigned*)&f;
      fu[0] = pack2(v0, v1);
      fu[1] = pack2(v2, v3);
      fu[2] = pack2(v4, v5);
      fu[3] = pack2(v6, v7);
      frag[rb] = f;
    }
#pragma unroll
    for (int i = 0; i < 4; i++)
#pragma unroll
      for (int j = 0; j < 4; j++)
        acc[i][j] = __builtin_amdgcn_mfma_f32_16x16x32_bf16(frag[i], frag[j],
                                                            acc[i][j], 0, 0, 0);
    if (s + 1 < NSTEP) {
#pragma unroll
      for (int rb = 0; rb < 4; rb++) {
        cur[rb][0] = nxt[rb][0];
        cur[rb][1] = nxt[rb][1];
      }
    }
  }

  // two-round wave reduce in 32KB LDS (keeps 3 blocks/CU)
  __shared__ float red[2][4096];
  __shared__ float swave[4][64];
  if (w >= 2) {
#pragma unroll
    for (int i = 0; i < 4; i++)
#pragma unroll
      for (int j = 0; j < 4; j++)
#pragma unroll
        for (int r = 0; r < 4; r++)
          red[w - 2][(i * 16 + quad * 4 + r) * 64 + j * 16 + col] = acc[i][j][r];
  }
  // channel sums: reduce csum across quads, stash per wave
#pragma unroll
  for (int rb = 0; rb < 4; rb++) {
    float c0 = csum[rb];
    c0 += __shfl_xor(c0, 16);
    c0 += __shfl_xor(c0, 32);
    if (lane < 16) swave[w][rb * 16 + lane] = c0;
  }
  __syncthreads();
  if (w < 2) {
#pragma unroll
    for (int i = 0; i < 4; i++)
#pragma unroll
      for (int j = 0; j < 4; j++)
#pragma unroll
        for (int r = 0; r < 4; r++)
          red[w][(i * 16 + quad * 4 + r) * 64 + j * 16 + col] += acc[i][j][r];
  }
  __syncthreads();
  float4* cp = (float4*)(covpart + (size_t)(b * NCHUNK + chunk) * 4096);
  const float4* r0 = (const float4*)red[0];
  const float4* r1 = (const float4*)red[1];
#pragma unroll
  for (int e = 0; e < 4; e++) {
    int idx = tid + 256 * e;
    float4 a = r0[idx], bb = r1[idx];
    a.x += bb.x; a.y += bb.y; a.z += bb.z; a.w += bb.w;
    cp[idx] = a;
  }
  if (tid < 64)
    sumpart[(size_t)(b * NCHUNK + chunk) * 64 + tid] =
        ((swave[0][tid] + swave[1][tid]) + (swave[2][tid] + swave[3][tid]));
}

// ---------------- K2: reduce + Newton-Schulz + gate MLP ----------------
__device__ __forceinline__ void mm64(short* __restrict__ D, const short* __restrict__ A,
                                     const short* __restrict__ Bm, int tid) {
  int w = tid >> 6, lane = tid & 63, quad = lane >> 4, col = lane & 15;
  f32x4 acc[4];
#pragma unroll
  for (int j = 0; j < 4; j++) acc[j] = (f32x4){0.f, 0.f, 0.f, 0.f};
#pragma unroll
  for (int ks = 0; ks < 2; ks++) {
    int k0 = ks * 32 + quad * 8;
    bf16x8 fa = *(const bf16x8*)(A + (w * 16 + col) * 64 + k0);
#pragma unroll
    for (int j = 0; j < 4; j++) {
      bf16x8 fb = *(const bf16x8*)(Bm + (j * 16 + col) * 64 + k0);
      acc[j] = __builtin_amdgcn_mfma_f32_16x16x32_bf16(fa, fb, acc[j], 0, 0, 0);
    }
  }
#pragma unroll
  for (int j = 0; j < 4; j++)
#pragma unroll
    for (int r = 0; r < 4; r++)
      D[(w * 16 + quad * 4 + r) * 64 + j * 16 + col] = f2bf(acc[j][r]);
}

__device__ __forceinline__ void mmcolsum(const short* __restrict__ A,
                                         const short* __restrict__ Bm,
                                         float* scol, int tid) {
  int w = tid >> 6, lane = tid & 63, quad = lane >> 4, col = lane & 15;
  f32x4 acc[4];
#pragma unroll
  for (int j = 0; j < 4; j++) acc[j] = (f32x4){0.f, 0.f, 0.f, 0.f};
#pragma unroll
  for (int ks = 0; ks < 2; ks++) {
    int k0 = ks * 32 + quad * 8;
    bf16x8 fa = *(const bf16x8*)(A + (w * 16 + col) * 64 + k0);
#pragma unroll
    for (int j = 0; j < 4; j++) {
      bf16x8 fb = *(const bf16x8*)(Bm + (j * 16 + col) * 64 + k0);
      acc[j] = __builtin_amdgcn_mfma_f32_16x16x32_bf16(fa, fb, acc[j], 0, 0, 0);
    }
  }
#pragma unroll
  for (int j = 0; j < 4; j++) {
    float t = (acc[j][0] + acc[j][1]) + (acc[j][2] + acc[j][3]);
    atomicAdd(&scol[j * 16 + col], t);
  }
}

__global__ __launch_bounds__(256) void ns_k(const float* __restrict__ covpart,
                                            const float* __restrict__ sumpart,
                                            const float* __restrict__ w1,
                                            const float* __restrict__ pb1,
                                            const float* __restrict__ w2,
                                            const float* __restrict__ pb2,
                                            float* __restrict__ gatews) {
  __shared__ __align__(16) short nb0[4096], nb1[4096], nb2[4096], nb3[4096], nb4[4096];
  __shared__ __align__(16) float gbuf[4096];
  __shared__ float mu[64];
  __shared__ float scol[64];
  __shared__ float hbuf[8];
  __shared__ float normA_sh;
  int b = blockIdx.x;
  int tid = threadIdx.x;

  // reduce the NCHUNK partial Grams for this batch (L2-resident)
  const float4* cp = (const float4*)covpart + (size_t)b * NCHUNK * 1024;
  float4* gb4 = (float4*)gbuf;
#pragma unroll
  for (int e = 0; e < 4; e++) {
    int idx = tid + 256 * e;
    float4 s = {0.f, 0.f, 0.f, 0.f};
    for (int ch = 0; ch < NCHUNK; ch++) {
      float4 v = cp[(size_t)ch * 1024 + idx];
      s.x += v.x; s.y += v.y; s.z += v.z; s.w += v.w;
    }
    gb4[idx] = s;
  }
  if (tid < 64) {
    float s = 0.f;
    for (int ch = 0; ch < NCHUNK; ch++) s += sumpart[(size_t)(b * NCHUNK + ch) * 64 + tid];
    mu[tid] = s * (1.0f / MM);
  }
  __syncthreads();
  if (tid < 64) {
    float d = gbuf[tid * 65] * (1.0f / MM) - mu[tid] * mu[tid];
#pragma unroll
    for (int off = 32; off >= 1; off >>= 1) d += __shfl_down(d, off);
    if (tid == 0) normA_sh = d;
  }
  __syncthreads();
  float rn = 1.0f / normA_sh;
  // A -> nb0, Z = ZY0 = 1.5I - 0.5A -> nb1
#pragma unroll
  for (int e = 0; e < 16; e++) {
    int idx = tid + 256 * e;
    int r = idx >> 6, c = idx & 63;
    float cv = gbuf[idx] * (1.0f / MM) - mu[r] * mu[c];
    float a = cv * rn;
    nb0[idx] = f2bf(a);
    nb1[idx] = f2bf((r == c ? 1.5f : 0.0f) - 0.5f * a);
  }
  __syncthreads();
  mm64(nb2, nb0, nb1, tid);  // Y = A @ ZY0
  __syncthreads();
  short *pY = nb2, *pZ = nb1, *s0 = nb3, *s1 = nb4, *s2 = nb0;
  for (int it = 0; it < 3; ++it) {
#pragma unroll
    for (int e = 0; e < 16; e++) {  // T = 1.5I - 0.5 Z -> s0
      int idx = tid + 256 * e;
      int r = idx >> 6, c = idx & 63;
      float z = bf2f(pZ[idx]);
      s0[idx] = f2bf((r == c ? 1.5f : 0.0f) - 0.5f * z);
    }
    __syncthreads();
    mm64(s1, s0, pY, tid);  // W = T @ Y
    __syncthreads();
    mm64(s2, pY, s1, tid);  // Ynew = Y @ W
    mm64(s0, s1, pZ, tid);  // Znew = W @ Z
    __syncthreads();
    short* oY = pY; short* oZ = pZ; short* oW = s1;
    pY = s2; pZ = s0; s0 = oY; s1 = oZ; s2 = oW;
  }
  mm64(s0, pZ, pY, tid);  // P = Z @ Y
  __syncthreads();
#pragma unroll
  for (int e = 0; e < 16; e++) {  // s0 = 3I - P
    int idx = tid + 256 * e;
    int r = idx >> 6, c = idx & 63;
    float p = bf2f(s0[idx]);
    s0[idx] = f2bf((r == c ? 3.0f : 0.0f) - p);
  }
  if (tid < 64) scol[tid] = 0.0f;
  __syncthreads();
  mmcolsum(pY, s0, scol, tid);  // column sums of R = Y @ (3I - P)
  __syncthreads();
  if (tid < 8) {
    float sc = 0.5f * sqrtf(normA_sh) * (1.0f / 64.0f);
    float acc = pb1[tid];
    for (int c = 0; c < 64; c++) acc += scol[c] * sc * w1[tid * 64 + c];
    hbuf[tid] = fmaxf(acc, 0.0f);
  }
  __syncthreads();
  if (tid < 64) {
    float acc = pb2[tid];
#pragma unroll
    for (int j = 0; j < 8; j++) acc += hbuf[j] * w2[tid * 8 + j];
    gatews[b * 64 + tid] = 1.0f / (1.0f + __expf(-acc));
  }
}

// ---------------- K3: out = x * gate ----------------
#define N4 (BB * CC * MM / 4)  // 4718592 float4s; 9216/4 = 2304 float4 per (b,c)
__global__ __launch_bounds__(256) void gate_mul(const float* __restrict__ x,
                                                const float* __restrict__ gatews,
                                                float* __restrict__ out) {
  int i = blockIdx.x * 256 + threadIdx.x;
  int bc = i / 2304;
  float g = gatews[bc];
  float4 v = ((const float4*)x)[i];
  v.x *= g; v.y *= g; v.z *= g; v.w *= g;
  ((float4*)out)[i] = v;
}

extern "C" void kernel_launch(void* const* d_in, const int* in_sizes, int n_in,
                              void* d_out, int out_size, void* d_ws, size_t ws_size,
                              hipStream_t stream) {
  const float* x = (const float*)d_in[0];
  const float* w1 = (const float*)d_in[1];
  const float* b1 = (const float*)d_in[2];
  const float* w2 = (const float*)d_in[3];
  const float* b2 = (const float*)d_in[4];
  float* out = (float*)d_out;
  float* ws = (float*)d_ws;
  float* covpart = ws;                                   // 32*24*4096 fp32 (12.6 MB)
  float* sumpart = covpart + (size_t)BB * NCHUNK * 4096; // 32*24*64 fp32
  float* gatews = sumpart + (size_t)BB * NCHUNK * 64;    // 32*64 fp32

  gram_k<<<BB * NCHUNK, 256, 0, stream>>>(x, covpart, sumpart);
  ns_k<<<BB, 256, 0, stream>>>(covpart, sumpart, w1, b1, w2, b2, gatews);
  gate_mul<<<N4 / 256, 256, 0, stream>>>(x, gatews, out);
}